// Round 5
// baseline (3715.947 us; speedup 1.0000x reference)
//
#include <hip/hip_runtime.h>
#include <math.h>

namespace {

constexpr int Bc = 16, Tc = 256, Mc = 256, Dc = 1024, Hc = 16;
constexpr int Sc = Mc + Tc;      // 512
constexpr int HDc = Dc / Hc;     // 64
constexpr int MLPHc = 4 * Dc;    // 4096
constexpr int TCc = 64;          // attention t-chunk (4 chunks)
constexpr float EPSc = 1e-5f;

using short8v = __attribute__((ext_vector_type(8))) short;   // 8 bf16 frag
using f32x4 = __attribute__((ext_vector_type(4))) float;     // C/D frag

__device__ inline unsigned short f2bf(float f) {  // RNE fp32->bf16
  const unsigned u = __float_as_uint(f);
  return (unsigned short)((u + 0x7fffu + ((u >> 16) & 1u)) >> 16);
}
__device__ inline float bf2f(unsigned short h) {
  return __uint_as_float((unsigned)h << 16);
}

// ---------------------------------------------------------------------------
// Split-bf16 MFMA GEMM for BT-format B (B stored [N][K] row-major).
//   C[z] = alpha * A[z] * B[z]^T-view (+ C[z] if ACCUM)
// A: MxK row-major. Both operands decompose to hi+lo bf16; acc in fp32 via
// 3 MFMA passes (hi*hi + hi*lo + lo*hi) -> ~1e-5 rel err.
// Tile BM x BN x BK32, 256 thr = 4 waves (2x2), wave tile (BM/2)x(BN/2),
// MFMA 16x16x32. M%BM==0, N%BN==0, K%32==0.
// Frag layout assumed: A row=lane&15, k=8*(lane>>4)+j (contig 8);
// B col=lane&15, same k; D col=lane&15, row=4*(lane>>4)+reg (HW-verified).
// LDS rows stride 40 ushort (32 data + 8 pad): frag b128 reads hit the
// 8-words/bank floor (conflict-free); staging ushort4 writes uniform.
// ---------------------------------------------------------------------------
template <int BM, int BN, bool ACCUM>
__global__ __launch_bounds__(256) void gemm_bt_mfma(
    const float* __restrict__ A, int lda, long sA1, long sA2,
    const float* __restrict__ Bm, int ldb, long sB1, long sB2,
    float* __restrict__ C, int ldc, long sC1, long sC2,
    int Kdim, int inner, float alpha) {
  constexpr int MT = BM / 32;  // m-tiles per wave
  constexpr int NT = BN / 32;  // n-tiles per wave
  __shared__ unsigned short AsH[BM * 40];
  __shared__ unsigned short AsL[BM * 40];
  __shared__ unsigned short BsH[BN * 40];
  __shared__ unsigned short BsL[BN * 40];

  const int tid = threadIdx.x;
  const int lane = tid & 63;
  const int wave = tid >> 6;
  const int wmBase = (wave >> 1) * (MT * 16);
  const int wnBase = (wave & 1) * (NT * 16);
  const int frow = lane & 15;
  const int fk = (lane >> 4) * 8;

  const int z = blockIdx.z;
  const int z1 = z / inner, z2 = z % inner;
  const float* Ab = A + (long)z1 * sA1 + (long)z2 * sA2;
  const float* Bb = Bm + (long)z1 * sB1 + (long)z2 * sB2;
  float* Cb = C + (long)z1 * sC1 + (long)z2 * sC2;
  const int m0 = blockIdx.y * BM;
  const int n0 = blockIdx.x * BN;

  f32x4 acc[MT][NT] = {};

  for (int k0 = 0; k0 < Kdim; k0 += 32) {
    __syncthreads();  // previous iteration's frag reads complete
    // stage A (BM x 32 fp32 -> hi/lo bf16), chunks of 4 floats
#pragma unroll
    for (int i = 0; i < BM / 32; ++i) {
      const int ch = tid + i * 256;
      const int m = ch >> 3, c = (ch & 7) * 4;
      const float4 v = *(const float4*)(Ab + (long)(m0 + m) * lda + (k0 + c));
      ushort4 h, l;
      h.x = f2bf(v.x); l.x = f2bf(v.x - bf2f(h.x));
      h.y = f2bf(v.y); l.y = f2bf(v.y - bf2f(h.y));
      h.z = f2bf(v.z); l.z = f2bf(v.z - bf2f(h.z));
      h.w = f2bf(v.w); l.w = f2bf(v.w - bf2f(h.w));
      *(ushort4*)&AsH[m * 40 + c] = h;
      *(ushort4*)&AsL[m * 40 + c] = l;
    }
    // stage B (BT: rows are n, contiguous k) same pattern
#pragma unroll
    for (int i = 0; i < BN / 32; ++i) {
      const int ch = tid + i * 256;
      const int n = ch >> 3, c = (ch & 7) * 4;
      const float4 v = *(const float4*)(Bb + (long)(n0 + n) * ldb + (k0 + c));
      ushort4 h, l;
      h.x = f2bf(v.x); l.x = f2bf(v.x - bf2f(h.x));
      h.y = f2bf(v.y); l.y = f2bf(v.y - bf2f(h.y));
      h.z = f2bf(v.z); l.z = f2bf(v.z - bf2f(h.z));
      h.w = f2bf(v.w); l.w = f2bf(v.w - bf2f(h.w));
      *(ushort4*)&BsH[n * 40 + c] = h;
      *(ushort4*)&BsL[n * 40 + c] = l;
    }
    __syncthreads();

    short8v Ah[MT], Al[MT], Bh[NT], Bl[NT];
#pragma unroll
    for (int mt = 0; mt < MT; ++mt) {
      const int r = wmBase + mt * 16 + frow;
      Ah[mt] = *(const short8v*)&AsH[r * 40 + fk];
      Al[mt] = *(const short8v*)&AsL[r * 40 + fk];
    }
#pragma unroll
    for (int nt = 0; nt < NT; ++nt) {
      const int r = wnBase + nt * 16 + frow;
      Bh[nt] = *(const short8v*)&BsH[r * 40 + fk];
      Bl[nt] = *(const short8v*)&BsL[r * 40 + fk];
    }
    // 3 passes, pass-outermost so same-acc MFMAs are far apart
#pragma unroll
    for (int mt = 0; mt < MT; ++mt)
#pragma unroll
      for (int nt = 0; nt < NT; ++nt)
        acc[mt][nt] = __builtin_amdgcn_mfma_f32_16x16x32_bf16(
            Ah[mt], Bh[nt], acc[mt][nt], 0, 0, 0);
#pragma unroll
    for (int mt = 0; mt < MT; ++mt)
#pragma unroll
      for (int nt = 0; nt < NT; ++nt)
        acc[mt][nt] = __builtin_amdgcn_mfma_f32_16x16x32_bf16(
            Ah[mt], Bl[nt], acc[mt][nt], 0, 0, 0);
#pragma unroll
    for (int mt = 0; mt < MT; ++mt)
#pragma unroll
      for (int nt = 0; nt < NT; ++nt)
        acc[mt][nt] = __builtin_amdgcn_mfma_f32_16x16x32_bf16(
            Al[mt], Bh[nt], acc[mt][nt], 0, 0, 0);
  }

#pragma unroll
  for (int mt = 0; mt < MT; ++mt)
#pragma unroll
    for (int nt = 0; nt < NT; ++nt)
#pragma unroll
      for (int r = 0; r < 4; ++r) {
        const int row = m0 + wmBase + mt * 16 + (lane >> 4) * 4 + r;
        const int col = n0 + wnBase + nt * 16 + (lane & 15);
        float* cp = Cb + (long)row * ldc + col;
        float v = acc[mt][nt][r] * alpha;
        if (ACCUM) v += *cp;
        *cp = v;
      }
}

// ---------------------------------------------------------------------------
// fp32 64x64 tile GEMM (kept for PV and as audited fallback).
// ---------------------------------------------------------------------------
template <bool BT, bool ACCUM, bool RELU>
__global__ __launch_bounds__(256) void gemm_kernel(
    const float* __restrict__ A, int lda, long sA1, long sA2,
    const float* __restrict__ Bm, int ldb, long sB1, long sB2,
    float* __restrict__ C, int ldc, long sC1, long sC2,
    int Kdim, int inner, const float* __restrict__ bias, float alpha) {
  __shared__ float As[16][68];
  __shared__ float Bs[16][68];

  const int tid = threadIdx.x;
  const int tx = tid & 15;
  const int ty = tid >> 4;
  const int z = blockIdx.z;
  const int z1 = z / inner, z2 = z % inner;
  const float* Ab = A + (long)z1 * sA1 + (long)z2 * sA2;
  const float* Bb = Bm + (long)z1 * sB1 + (long)z2 * sB2;
  float* Cb = C + (long)z1 * sC1 + (long)z2 * sC2;
  const int m0 = blockIdx.y * 64;
  const int n0 = blockIdx.x * 64;

  const int arow = tid >> 2;
  const int acol = (tid & 3) * 4;

  float acc[4][4] = {};

  for (int k0 = 0; k0 < Kdim; k0 += 16) {
    const float4 av =
        *(const float4*)(Ab + (long)(m0 + arow) * lda + (k0 + acol));
    float4 bv;
    if (!BT) {
      bv = *(const float4*)(Bb + (long)(k0 + (tid >> 4)) * ldb +
                            (n0 + (tid & 15) * 4));
    } else {
      bv = *(const float4*)(Bb + (long)(n0 + arow) * ldb + (k0 + acol));
    }
    __syncthreads();
    As[acol + 0][arow] = av.x;
    As[acol + 1][arow] = av.y;
    As[acol + 2][arow] = av.z;
    As[acol + 3][arow] = av.w;
    if (!BT) {
      *(float4*)&Bs[tid >> 4][(tid & 15) * 4] = bv;
    } else {
      Bs[acol + 0][arow] = bv.x;
      Bs[acol + 1][arow] = bv.y;
      Bs[acol + 2][arow] = bv.z;
      Bs[acol + 3][arow] = bv.w;
    }
    __syncthreads();
#pragma unroll
    for (int k = 0; k < 16; ++k) {
      float a0[4], b0[4];
      *(float4*)a0 = *(const float4*)&As[k][ty * 4];
      *(float4*)b0 = *(const float4*)&Bs[k][tx * 4];
#pragma unroll
      for (int i = 0; i < 4; ++i)
#pragma unroll
        for (int j = 0; j < 4; ++j) acc[i][j] = fmaf(a0[i], b0[j], acc[i][j]);
    }
  }

#pragma unroll
  for (int i = 0; i < 4; ++i) {
    const int row = m0 + ty * 4 + i;
    float4 v;
    v.x = acc[i][0] * alpha;
    v.y = acc[i][1] * alpha;
    v.z = acc[i][2] * alpha;
    v.w = acc[i][3] * alpha;
    if (bias != nullptr) {
      const float4 bv = *(const float4*)(bias + n0 + tx * 4);
      v.x += bv.x; v.y += bv.y; v.z += bv.z; v.w += bv.w;
    }
    float* cp = Cb + (long)row * ldc + (n0 + tx * 4);
    if (ACCUM) {
      const float4 ov = *(const float4*)cp;
      v.x += ov.x; v.y += ov.y; v.z += ov.z; v.w += ov.w;
    }
    if (RELU) {
      v.x = fmaxf(v.x, 0.f); v.y = fmaxf(v.y, 0.f);
      v.z = fmaxf(v.z, 0.f); v.w = fmaxf(v.w, 0.f);
    }
    *(float4*)cp = v;
  }
}

// ---------------------------------------------------------------------------
// fp32 128x128 tile, split 8x8 microtile (2-way LDS aliasing everywhere).
// ---------------------------------------------------------------------------
template <bool BT, bool ACCUM, bool RELU>
__global__ __launch_bounds__(256) void gemm128_kernel(
    const float* __restrict__ A, int lda, long sA1, long sA2,
    const float* __restrict__ Bm, int ldb, long sB1, long sB2,
    float* __restrict__ C, int ldc, long sC1, long sC2,
    int Kdim, int inner, const float* __restrict__ bias, float alpha) {
  __shared__ float As[16][132];
  __shared__ float Bs[16][132];

  const int tid = threadIdx.x;
  const int tx = tid & 15;
  const int ty = tid >> 4;
  const int z = blockIdx.z;
  const int z1 = z / inner, z2 = z % inner;
  const float* Ab = A + (long)z1 * sA1 + (long)z2 * sA2;
  const float* Bb = Bm + (long)z1 * sB1 + (long)z2 * sB2;
  float* Cb = C + (long)z1 * sC1 + (long)z2 * sC2;
  const int m0 = blockIdx.y * 128;
  const int n0 = blockIdx.x * 128;

  const int arow = tid >> 1;
  const int acol = (tid & 1) * 8;

  float acc[8][8] = {};

  for (int k0 = 0; k0 < Kdim; k0 += 16) {
    const float* ap = Ab + (long)(m0 + arow) * lda + (k0 + acol);
    const float4 av0 = *(const float4*)ap;
    const float4 av1 = *(const float4*)(ap + 4);
    float4 bv0, bv1;
    if (!BT) {
      const float* bp = Bb + (long)(k0 + ty) * ldb + (n0 + tx * 8);
      bv0 = *(const float4*)bp;
      bv1 = *(const float4*)(bp + 4);
    } else {
      const float* bp = Bb + (long)(n0 + arow) * ldb + (k0 + acol);
      bv0 = *(const float4*)bp;
      bv1 = *(const float4*)(bp + 4);
    }
    __syncthreads();
    As[acol + 0][arow] = av0.x;
    As[acol + 1][arow] = av0.y;
    As[acol + 2][arow] = av0.z;
    As[acol + 3][arow] = av0.w;
    As[acol + 4][arow] = av1.x;
    As[acol + 5][arow] = av1.y;
    As[acol + 6][arow] = av1.z;
    As[acol + 7][arow] = av1.w;
    if (!BT) {
      *(float4*)&Bs[ty][tx * 8] = bv0;
      *(float4*)&Bs[ty][tx * 8 + 4] = bv1;
    } else {
      Bs[acol + 0][arow] = bv0.x;
      Bs[acol + 1][arow] = bv0.y;
      Bs[acol + 2][arow] = bv0.z;
      Bs[acol + 3][arow] = bv0.w;
      Bs[acol + 4][arow] = bv1.x;
      Bs[acol + 5][arow] = bv1.y;
      Bs[acol + 6][arow] = bv1.z;
      Bs[acol + 7][arow] = bv1.w;
    }
    __syncthreads();
#pragma unroll
    for (int k = 0; k < 16; ++k) {
      float a0[8], b0[8];
      *(float4*)(a0 + 0) = *(const float4*)&As[k][ty * 4];
      *(float4*)(a0 + 4) = *(const float4*)&As[k][64 + ty * 4];
      *(float4*)(b0 + 0) = *(const float4*)&Bs[k][tx * 4];
      *(float4*)(b0 + 4) = *(const float4*)&Bs[k][64 + tx * 4];
#pragma unroll
      for (int i = 0; i < 8; ++i)
#pragma unroll
        for (int j = 0; j < 8; ++j) acc[i][j] = fmaf(a0[i], b0[j], acc[i][j]);
    }
  }

  const float4 blo = bias ? *(const float4*)(bias + n0 + tx * 4)
                          : float4{0, 0, 0, 0};
  const float4 bhi = bias ? *(const float4*)(bias + n0 + 64 + tx * 4)
                          : float4{0, 0, 0, 0};
#pragma unroll
  for (int rh = 0; rh < 2; ++rh) {
#pragma unroll
    for (int i = 0; i < 4; ++i) {
      const int row = m0 + rh * 64 + ty * 4 + i;
      float4 vlo, vhi;
      vlo.x = acc[rh * 4 + i][0] * alpha + blo.x;
      vlo.y = acc[rh * 4 + i][1] * alpha + blo.y;
      vlo.z = acc[rh * 4 + i][2] * alpha + blo.z;
      vlo.w = acc[rh * 4 + i][3] * alpha + blo.w;
      vhi.x = acc[rh * 4 + i][4] * alpha + bhi.x;
      vhi.y = acc[rh * 4 + i][5] * alpha + bhi.y;
      vhi.z = acc[rh * 4 + i][6] * alpha + bhi.z;
      vhi.w = acc[rh * 4 + i][7] * alpha + bhi.w;
      float* cplo = Cb + (long)row * ldc + (n0 + tx * 4);
      float* cphi = Cb + (long)row * ldc + (n0 + 64 + tx * 4);
      if (ACCUM) {
        const float4 o0 = *(const float4*)cplo;
        const float4 o1 = *(const float4*)cphi;
        vlo.x += o0.x; vlo.y += o0.y; vlo.z += o0.z; vlo.w += o0.w;
        vhi.x += o1.x; vhi.y += o1.y; vhi.z += o1.z; vhi.w += o1.w;
      }
      if (RELU) {
        vlo.x = fmaxf(vlo.x, 0.f); vlo.y = fmaxf(vlo.y, 0.f);
        vlo.z = fmaxf(vlo.z, 0.f); vlo.w = fmaxf(vlo.w, 0.f);
        vhi.x = fmaxf(vhi.x, 0.f); vhi.y = fmaxf(vhi.y, 0.f);
        vhi.z = fmaxf(vhi.z, 0.f); vhi.w = fmaxf(vhi.w, 0.f);
      }
      *(float4*)cplo = vlo;
      *(float4*)cphi = vhi;
    }
  }
}

// ---------------------------------------------------------------------------
// block-wide reductions (256 threads = 4 waves of 64)
// ---------------------------------------------------------------------------
template <int OP>  // 0 = sum, 1 = max
__device__ inline float block_reduce(float v, float* sbuf) {
#pragma unroll
  for (int o = 32; o > 0; o >>= 1) {
    const float other = __shfl_down(v, o);
    v = OP ? fmaxf(v, other) : (v + other);
  }
  const int wv = threadIdx.x >> 6, ln = threadIdx.x & 63;
  if (ln == 0) sbuf[wv] = v;
  __syncthreads();
  v = OP ? fmaxf(fmaxf(sbuf[0], sbuf[1]), fmaxf(sbuf[2], sbuf[3]))
         : (sbuf[0] + sbuf[1] + sbuf[2] + sbuf[3]);
  __syncthreads();
  return v;
}

__global__ __launch_bounds__(256) void ln_kernel(
    const float* __restrict__ in, const float* __restrict__ w,
    const float* __restrict__ b, float* __restrict__ out, int mode) {
  __shared__ float red[4];
  const int r = blockIdx.x;
  const int c = threadIdx.x * 4;
  const float4 v = *(const float4*)(in + (long)r * Dc + c);
  float s = v.x + v.y + v.z + v.w;
  float q = v.x * v.x + v.y * v.y + v.z * v.z + v.w * v.w;
  s = block_reduce<0>(s, red);
  q = block_reduce<0>(q, red);
  const float mean = s * (1.0f / Dc);
  const float var = q * (1.0f / Dc) - mean * mean;
  const float rstd = rsqrtf(var + EPSc);
  float* orow;
  if (mode == 0) {
    orow = out + (long)r * Dc;
  } else {
    const int bb = r / Tc, t = r % Tc;
    orow = out + ((long)bb * Sc + Mc + t) * Dc;
  }
  const float4 wv = *(const float4*)(w + c);
  const float4 bv = *(const float4*)(b + c);
  float4 o;
  o.x = (v.x - mean) * rstd * wv.x + bv.x;
  o.y = (v.y - mean) * rstd * wv.y + bv.y;
  o.z = (v.z - mean) * rstd * wv.z + bv.z;
  o.w = (v.w - mean) * rstd * wv.w + bv.w;
  *(float4*)(orow + c) = o;
}

__global__ __launch_bounds__(256) void copy_mem_kernel(
    const float* __restrict__ mem, float* __restrict__ kv) {
  const long i4 = (long)blockIdx.x * blockDim.x + threadIdx.x;
  const long n4 = (long)Bc * Mc * Dc / 4;
  if (i4 >= n4) return;
  const long e = i4 * 4;
  const int b = (int)(e / ((long)Mc * Dc));
  const long rem = e - (long)b * Mc * Dc;
  *(float4*)(kv + (long)b * Sc * Dc + rem) = *(const float4*)(mem + e);
}

__global__ __launch_bounds__(256) void softmax_kernel(float* __restrict__ attn) {
  __shared__ float red[4];
  float* row = attn + (long)blockIdx.x * Sc;
  const int c = threadIdx.x * 2;
  float2 v = *(float2*)(row + c);
  float mx = block_reduce<1>(fmaxf(v.x, v.y), red);
  const float e0 = expf(v.x - mx);
  const float e1 = expf(v.y - mx);
  const float inv = 1.0f / block_reduce<0>(e0 + e1, red);
  v.x = e0 * inv;
  v.y = e1 * inv;
  *(float2*)(row + c) = v;
}

__global__ __launch_bounds__(256) void gate_apply_kernel(
    const float* __restrict__ G, const float* __restrict__ w,
    const float* __restrict__ b, const float* __restrict__ a,
    const float* __restrict__ res, float* __restrict__ out) {
  __shared__ float red[4];
  const long r = blockIdx.x;
  const int c = threadIdx.x * 4;
  const float4 v = *(const float4*)(G + r * Dc + c);
  float s = v.x + v.y + v.z + v.w;
  float q = v.x * v.x + v.y * v.y + v.z * v.z + v.w * v.w;
  s = block_reduce<0>(s, red);
  q = block_reduce<0>(q, red);
  const float mean = s * (1.0f / Dc);
  const float var = q * (1.0f / Dc) - mean * mean;
  const float rstd = rsqrtf(var + EPSc);
  const float4 wv = *(const float4*)(w + c);
  const float4 bv = *(const float4*)(b + c);
  const float4 av = *(const float4*)(a + r * Dc + c);
  const float4 rv = *(const float4*)(res + r * Dc + c);
  float4 o;
  {
    const float g = 1.0f / (1.0f + expf(-((v.x - mean) * rstd * wv.x + bv.x)));
    o.x = g * av.x + (1.0f - g) * rv.x;
  }
  {
    const float g = 1.0f / (1.0f + expf(-((v.y - mean) * rstd * wv.y + bv.y)));
    o.y = g * av.y + (1.0f - g) * rv.y;
  }
  {
    const float g = 1.0f / (1.0f + expf(-((v.z - mean) * rstd * wv.z + bv.z)));
    o.z = g * av.z + (1.0f - g) * rv.z;
  }
  {
    const float g = 1.0f / (1.0f + expf(-((v.w - mean) * rstd * wv.w + bv.w)));
    o.w = g * av.w + (1.0f - g) * rv.w;
  }
  *(float4*)(out + r * Dc + c) = o;
}

}  // namespace

extern "C" void kernel_launch(void* const* d_in, const int* in_sizes, int n_in,
                              void* d_out, int out_size, void* d_ws,
                              size_t ws_size, hipStream_t stream) {
  const float* x = (const float*)d_in[0];
  const float* mem = (const float*)d_in[1];
  const float* rel = (const float*)d_in[2];
  const float* anw = (const float*)d_in[3];
  const float* anb = (const float*)d_in[4];
  const float* Wq = (const float*)d_in[5];
  const float* Wk = (const float*)d_in[6];
  const float* Wv = (const float*)d_in[7];
  const float* Wo = (const float*)d_in[8];
  const float* bo = (const float*)d_in[9];
  const float* Wr = (const float*)d_in[10];
  const float* agw = (const float*)d_in[11];
  const float* agnw = (const float*)d_in[12];
  const float* agnb = (const float*)d_in[13];
  const float* mnw = (const float*)d_in[14];
  const float* mnb = (const float*)d_in[15];
  const float* W1 = (const float*)d_in[16];
  const float* b1 = (const float*)d_in[17];
  const float* W2 = (const float*)d_in[18];
  const float* b2 = (const float*)d_in[19];
  const float* mgw = (const float*)d_in[20];
  const float* mgnw = (const float*)d_in[21];
  const float* mgnb = (const float*)d_in[22];

  // Slot-aliased workspace, peak 192 MiB:
  float* ws = (float*)d_ws;
  float* slot0 = ws;
  float* Q = slot0 + 8388608;
  float* slot2 = Q + 4194304;
  float* slot3 = slot2 + 16777216;
  float* slot4 = slot3 + 16777216;

  float* kv = slot0;
  float* attnc = slot0;  // [h][b][tt][s] — kv dead after K/V
  float* xn2 = slot0;
  float* Kb = slot2;
  float* Vb = slot2 + 8388608;
  float* hmlp = slot2;   // K,V dead in MLP phase
  float* Qp = slot3;     // [h][b][tt][D]
  float* aproj = slot3;  // Qp dead in attention phase-2
  float* G = slot3 + 4194304;
  float* x1 = slot3 + 8388608;
  float* pv = slot4;
  float* mbuf = slot4;
  float* G2 = G;

  const float scale = 0.125f;  // 1/sqrt(HD)

  // 1. kv[:, :M, :] = mem ; 2. kv[:, M:, :] = LN(x)
  copy_mem_kernel<<<(Bc * Mc * Dc / 4 + 255) / 256, 256, 0, stream>>>(mem, kv);
  ln_kernel<<<Bc * Tc, 256, 0, stream>>>(x, anw, anb, kv, 1);

  // 3. Q = xn @ Wq  (fp32 path)
  {
    dim3 g(Dc / 128, Tc / 128, Bc);
    gemm128_kernel<false, false, false><<<g, 256, 0, stream>>>(
        kv + (long)Mc * Dc, Dc, (long)Sc * Dc, 0, Wq, Dc, 0, 0, Q, Dc,
        (long)Tc * Dc, 0, Dc, 1, nullptr, 1.0f);
  }
  // 4/5. K,V = kv @ Wk / kv @ Wv  (fp32 path)
  {
    dim3 g(Dc / 128, Bc * Sc / 128, 1);
    gemm128_kernel<false, false, false><<<g, 256, 0, stream>>>(
        kv, Dc, 0, 0, Wk, Dc, 0, 0, Kb, Dc, 0, 0, Dc, 1, nullptr, 1.0f);
    gemm128_kernel<false, false, false><<<g, 256, 0, stream>>>(
        kv, Dc, 0, 0, Wv, Dc, 0, 0, Vb, Dc, 0, 0, Dc, 1, nullptr, 1.0f);
  }
  // kv dead from here.

  // 6. attention, t-chunked (TCc=64): BT GEMMs on split-bf16 MFMA.
  for (int tc = 0; tc < Tc / TCc; ++tc) {
    const int t0 = tc * TCc;
    // 6a. Qp[h,b,tt,:] = Q[b,t0+tt, h*64:] @ Wr_h^T   (z = h*B + b)
    {
      dim3 g(Dc / 64, TCc / 64, Hc * Bc);
      gemm_bt_mfma<64, 64, false><<<g, 256, 0, stream>>>(
          Q + (long)t0 * Dc, Dc, HDc, (long)Tc * Dc, Wr, Dc, HDc, 0, Qp, Dc,
          (long)Bc * TCc * Dc, (long)TCc * Dc, HDc, Bc, 1.0f);
    }
    // 6b. content: attnc[h,b,tt,s] = scale * Q @ K^T   (z = b*H + h)
    {
      dim3 g(Sc / 64, TCc / 64, Bc * Hc);
      gemm_bt_mfma<64, 64, false><<<g, 256, 0, stream>>>(
          Q + (long)t0 * Dc, Dc, (long)Tc * Dc, HDc, Kb, Dc, (long)Sc * Dc,
          HDc, attnc, Sc, (long)TCc * Sc, (long)Bc * TCc * Sc, HDc, Hc, scale);
    }
    // 6c. pos: attnc[h,b,tt,s] += scale * Qp[:,tt,:] @ rel[t0+tt]^T (z = tt)
    {
      dim3 g(Sc / 128, (Hc * Bc) / 128, TCc);
      gemm_bt_mfma<128, 128, true><<<g, 256, 0, stream>>>(
          Qp, TCc * Dc, Dc, 0, rel + (long)t0 * Sc * Dc, Dc, (long)Sc * Dc, 0,
          attnc, TCc * Sc, Sc, 0, Dc, 1, scale);
    }
    // 6d. softmax over s
    softmax_kernel<<<Hc * Bc * TCc, 256, 0, stream>>>(attnc);
    // 6e. pv[b,t0+tt,h,:] = P @ V   (fp32, non-BT, small)
    {
      dim3 g(HDc / 64, TCc / 64, Bc * Hc);
      gemm_kernel<false, false, false><<<g, 256, 0, stream>>>(
          attnc, Sc, (long)TCc * Sc, (long)Bc * TCc * Sc, Vb, Dc,
          (long)Sc * Dc, HDc, pv + (long)t0 * Dc, Dc, (long)Tc * Dc, HDc, Sc,
          Hc, nullptr, 1.0f);
    }
  }
  // Qp dead from here.

  // 7. aproj = pv @ Wo + bo ; 8. G = x @ agw_top + aproj @ agw_bot
  {
    dim3 g(Dc / 128, Bc * Tc / 128, 1);
    gemm128_kernel<false, false, false><<<g, 256, 0, stream>>>(
        pv, Dc, 0, 0, Wo, Dc, 0, 0, aproj, Dc, 0, 0, Dc, 1, bo, 1.0f);
    gemm128_kernel<false, false, false><<<g, 256, 0, stream>>>(
        x, Dc, 0, 0, agw, Dc, 0, 0, G, Dc, 0, 0, Dc, 1, nullptr, 1.0f);
    gemm128_kernel<false, true, false><<<g, 256, 0, stream>>>(
        aproj, Dc, 0, 0, agw + (long)Dc * Dc, Dc, 0, 0, G, Dc, 0, 0, Dc, 1,
        nullptr, 1.0f);
  }
  // 9. x1 = sigmoid(LN(G)) * aproj + (1-g) * x
  gate_apply_kernel<<<Bc * Tc, 256, 0, stream>>>(G, agnw, agnb, aproj, x, x1);
  // 10. xn2 = LN(x1)
  ln_kernel<<<Bc * Tc, 256, 0, stream>>>(x1, mnw, mnb, xn2, 0);
  // 11. hmlp = relu(xn2 @ W1 + b1)
  {
    dim3 g(MLPHc / 128, Bc * Tc / 128, 1);
    gemm128_kernel<false, false, true><<<g, 256, 0, stream>>>(
        xn2, Dc, 0, 0, W1, MLPHc, 0, 0, hmlp, MLPHc, 0, 0, Dc, 1, b1, 1.0f);
  }
  // 12. mbuf = hmlp @ W2 + b2 ; 13. G2 = x1 @ mgw_top + mbuf @ mgw_bot
  {
    dim3 g(Dc / 128, Bc * Tc / 128, 1);
    gemm128_kernel<false, false, false><<<g, 256, 0, stream>>>(
        hmlp, MLPHc, 0, 0, W2, Dc, 0, 0, mbuf, Dc, 0, 0, MLPHc, 1, b2, 1.0f);
    gemm128_kernel<false, false, false><<<g, 256, 0, stream>>>(
        x1, Dc, 0, 0, mgw, Dc, 0, 0, G2, Dc, 0, 0, Dc, 1, nullptr, 1.0f);
    gemm128_kernel<false, true, false><<<g, 256, 0, stream>>>(
        mbuf, Dc, 0, 0, mgw + (long)Dc * Dc, Dc, 0, 0, G2, Dc, 0, 0, Dc, 1,
        nullptr, 1.0f);
  }
  // 14. out = sigmoid(LN(G2)) * mbuf + (1-g) * x1
  gate_apply_kernel<<<Bc * Tc, 256, 0, stream>>>(G2, mgnw, mgnb, mbuf, x1,
                                                 (float*)d_out);
}